// Round 10
// baseline (294.624 us; speedup 1.0000x reference)
//
#include <hip/hip_runtime.h>

#define NVOX 32000
#define NPTS 1024000
#define KBLK 2000      // k2/k3 blocks (4 waves each -> 8000 waves)
#define KWAV 8000
#define KVPW 4         // voxels per wave: 8000*4 = 32000
#define BIGF 1e30f

typedef __attribute__((ext_vector_type(8)))  short bf8v;   // 8 bf16 (4 VGPRs)
typedef __attribute__((ext_vector_type(16))) float f16x;   // MFMA 32x32 accum

// split x = hi + lo (both trunc-bf16); residual error ~2^-16 relative
__device__ __forceinline__ void split2(float x, short* hi, short* lo) {
    const unsigned u = __float_as_uint(x);
    *hi = (short)(u >> 16);
    const float r = x - __uint_as_float(u & 0xFFFF0000u);   // exact
    *lo = (short)(__float_as_uint(r) >> 16);
}
__device__ __forceinline__ float rdlane(float v, int l) {
    return __int_as_float(__builtin_amdgcn_readlane(__float_as_int(v), l));
}

// ws layout: doubles first (atomic accumulators), then float params
// doubles: sF[44] | s2[64] | sfin[128] = 236 doubles = 472 floats
#define OF_W1S  480          // 128
#define OF_C1S  (480+128)    // 16

// ---------------- kz: zero the stats accumulators ----------------
__global__ void kz(double* __restrict__ s) {
    if (threadIdx.x < 236) s[threadIdx.x] = 0.0;
}

// ---------------- k1: moment accumulation (Sf[8], Sff upper[36]) ----------------
__global__ __launch_bounds__(256) void k1(const float* __restrict__ vox,
                                          const int* __restrict__ coords,
                                          double* __restrict__ sF) {
    float S[8], U[36];
#pragma unroll
    for (int a = 0; a < 8; a++) S[a] = 0.f;
#pragma unroll
    for (int a = 0; a < 36; a++) U[a] = 0.f;
    const int stride = gridDim.x * blockDim.x;
    for (int i = blockIdx.x * blockDim.x + threadIdx.x; i < NPTS; i += stride) {
        const int vx = i >> 5;
        const float4 q = reinterpret_cast<const float4*>(vox)[i];
        const int4 c4 = reinterpret_cast<const int4*>(coords)[vx];
        const float cx = ((float)c4.w + 0.5f) * 0.16f;
        const float cy = ((float)c4.z + 0.5f) * 0.16f - 39.68f;
        const float cz = ((float)c4.y + 0.5f) * 4.0f  - 3.0f;
        const float f[8] = {q.x, q.y, q.z, q.x - cx, q.y - cy, q.z - cz, q.w, q.z};
        int u = 0;
#pragma unroll
        for (int a = 0; a < 8; a++) {
            S[a] += f[a];
#pragma unroll
            for (int b = a; b < 8; b++) { U[u] = fmaf(f[a], f[b], U[u]); u++; }
        }
    }
    __shared__ float red[4][44];
    const int lane = threadIdx.x & 63, wv = threadIdx.x >> 6;
#pragma unroll
    for (int t = 0; t < 44; t++) {
        float s = (t < 8) ? S[t] : U[t - 8];
#pragma unroll
        for (int m = 1; m < 64; m <<= 1) s += __shfl_xor(s, m);
        if (lane == 0) red[wv][t] = s;
    }
    __syncthreads();
    if (threadIdx.x < 44) {
        const float t = red[0][threadIdx.x] + red[1][threadIdx.x] +
                        red[2][threadIdx.x] + red[3][threadIdx.x];
        atomicAdd(&sF[threadIdx.x], (double)t);
    }
}

// ---------------- kr1: moments -> h1 stats (quadratic form) -> scaled W1 + c1 ----------------
__global__ __launch_bounds__(128) void kr1(const double* __restrict__ sF,
                                           const float* __restrict__ W1,
                                           const float* __restrict__ g1,
                                           const float* __restrict__ b1,
                                           float* __restrict__ w1s,
                                           float* __restrict__ c1s) {
    __shared__ float a1f[16];
    const int t = threadIdx.x;
    if (t < 16) {
        double w[8];
#pragma unroll
        for (int c = 0; c < 8; c++) w[c] = (double)W1[t * 8 + c];
        double mu = 0.0;
#pragma unroll
        for (int c = 0; c < 8; c++) mu += w[c] * sF[c];
        double sq = 0.0;
        int u = 8;
        for (int a = 0; a < 8; a++)
            for (int b = a; b < 8; b++) {
                const double F = sF[u++];
                sq += (a == b ? 1.0 : 2.0) * w[a] * w[b] * F;
            }
        const double m = mu * (1.0 / NPTS);
        const double v = sq * (1.0 / NPTS) - m * m;
        const float inv = rsqrtf((float)v + 1e-3f);
        const float aa = g1[t] * inv;
        a1f[t] = aa;
        c1s[t] = b1[t] - (float)m * aa;
    }
    __syncthreads();
    w1s[t] = a1f[t >> 3] * W1[t];
}

// ---------------- k2: split-bf16 MFMA layer-2, stats of h2pre + fp32 extrema -> d_out ----------------
// (256,4): VGPR ~52 naturally -> up to 8 waves/SIMD without spills.
// (256,8) forced VGPR=32 and spilled: +49 MB scratch traffic (round 8).
__global__ __launch_bounds__(256, 4) void k2(const float* __restrict__ vox,
                                             const int* __restrict__ coords,
                                             const int* __restrict__ nump,
                                             const float* __restrict__ w1s,
                                             const float* __restrict__ c1s,
                                             const float* __restrict__ W2,
                                             const float* __restrict__ g2,
                                             double* __restrict__ s2,
                                             float* __restrict__ outp) {
    const int l = threadIdx.x & 63, wv = threadIdx.x >> 6;
    const int p = l & 31, hf = l >> 5;

    bf8v b1h, b1l, b2h, b2l;
#pragma unroll
    for (int i = 0; i < 8; i++) {
        short h_, l_;
        split2(W2[p * 32 + 8 * hf + i], &h_, &l_);       b1h[i] = h_; b1l[i] = l_;
        split2(W2[p * 32 + 16 + 8 * hf + i], &h_, &l_);  b2h[i] = h_; b2l[i] = l_;
    }
    // sign(a2) == sign(g2); work in xs = sign-flipped space so one max covers both.
    const unsigned sbit = (g2[p] >= 0.f) ? 0u : 0x80000000u;

    float tsum = 0.f, tsq = 0.f;
    const int gw = blockIdx.x * 4 + wv;
#pragma unroll 1
    for (int v = 0; v < KVPW; ++v) {
        const int vx = gw + v * KWAV;
        const int4 c4 = reinterpret_cast<const int4*>(coords)[vx];
        const int np = nump[vx];
        const float4 q = reinterpret_cast<const float4*>(vox)[(vx << 5) + p];
        const float cx = ((float)c4.w + 0.5f) * 0.16f;
        const float cy = ((float)c4.z + 0.5f) * 0.16f - 39.68f;
        const float cz = ((float)c4.y + 0.5f) * 4.0f  - 3.0f;
        const float f[8] = {q.x, q.y, q.z, q.x - cx, q.y - cy, q.z - cz, q.w, q.z};
        float mine[8], mx[8];
#pragma unroll
        for (int i = 0; i < 8; i++) {
            float s0 = c1s[i], s1v = c1s[8 + i];
#pragma unroll
            for (int c = 0; c < 8; c++) {
                s0 = fmaf(f[c], w1s[i * 8 + c], s0);
                s1v = fmaf(f[c], w1s[(8 + i) * 8 + c], s1v);
            }
            mine[i] = fmaxf(hf ? s1v : s0, 0.f);
        }
#pragma unroll
        for (int i = 0; i < 8; i++) {
            float m = mine[i];
            m = fmaxf(m, __shfl_xor(m, 1));
            m = fmaxf(m, __shfl_xor(m, 2));
            m = fmaxf(m, __shfl_xor(m, 4));
            m = fmaxf(m, __shfl_xor(m, 8));
            m = fmaxf(m, __shfl_xor(m, 16));
            mx[i] = m;
        }
        const float mk = (p < np) ? 1.f : 0.f;
        bf8v a1h, a1l, a2h, a2l;
#pragma unroll
        for (int i = 0; i < 8; i++) {
            short h_, l_;
            split2(mk * mine[i], &h_, &l_);  a1h[i] = h_; a1l[i] = l_;
            split2(mk * mx[i], &h_, &l_);    a2h[i] = h_; a2l[i] = l_;
        }
        f16x d;
#pragma unroll
        for (int r = 0; r < 16; r++) d[r] = 0.f;
        d = __builtin_amdgcn_mfma_f32_32x32x16_bf16(a1h, b1h, d, 0, 0, 0);
        d = __builtin_amdgcn_mfma_f32_32x32x16_bf16(a1l, b1h, d, 0, 0, 0);
        d = __builtin_amdgcn_mfma_f32_32x32x16_bf16(a1h, b1l, d, 0, 0, 0);
        d = __builtin_amdgcn_mfma_f32_32x32x16_bf16(a2h, b2h, d, 0, 0, 0);
        d = __builtin_amdgcn_mfma_f32_32x32x16_bf16(a2l, b2h, d, 0, 0, 0);
        d = __builtin_amdgcn_mfma_f32_32x32x16_bf16(a2h, b2l, d, 0, 0, 0);

        // stats + extrema in xs-space (lane = channel p, rows (r&3)+8*(r>>2)+4*hf)
        float fx = -BIGF, mxv = -BIGF;
#pragma unroll
        for (int r = 0; r < 16; r++) {
            const int row = (r & 3) + 8 * (r >> 2) + 4 * hf;
            const float x = d[r];
            tsum += x;
            tsq = fmaf(x, x, tsq);
            const float xs = __uint_as_float(__float_as_uint(x) ^ sbit);
            fx = fmaxf(fx, xs);
            mxv = fmaxf(mxv, (row < np) ? xs : -BIGF);
        }
        fx  = fmaxf(fx,  __shfl_xor(fx, 32));
        mxv = fmaxf(mxv, __shfl_xor(mxv, 32));
        // lane l<32: masked extremum of channel l; lane>=32: full extremum of channel l-32
        const float e = __uint_as_float(__float_as_uint(hf ? fx : mxv) ^ sbit);
        outp[(vx << 6) + l] = e;
    }

    tsum += __shfl_xor(tsum, 32);
    tsq  += __shfl_xor(tsq, 32);
    __shared__ float red[4][64];
    if (l < 32) { red[wv][l] = tsum; red[wv][32 + l] = tsq; }
    __syncthreads();
    if (threadIdx.x < 64) {
        const float t = red[0][threadIdx.x] + red[1][threadIdx.x] +
                        red[2][threadIdx.x] + red[3][threadIdx.x];
        atomicAdd(&s2[threadIdx.x], (double)t);
    }
}

// ---------------- k3: (fused kr2) extrema -> voxel features -> fp32 Wf dot ----------------
__global__ __launch_bounds__(256, 4) void k3(const int* __restrict__ nump,
                                             const double* __restrict__ s2,
                                             const float* __restrict__ g2,
                                             const float* __restrict__ b2,
                                             const float* __restrict__ Wf,
                                             double* __restrict__ sfin,
                                             float* __restrict__ outp) {
    const int l = threadIdx.x & 63, wv = threadIdx.x >> 6;
    const int p = l & 31;

    // fused kr2: per-lane BN2 affine for channel p
    const double m2 = s2[p] * (1.0 / NPTS);
    const double v2 = s2[32 + p] * (1.0 / NPTS) - m2 * m2;
    const float a2v = g2[p] * rsqrtf((float)v2 + 1e-3f);
    const float c2v = b2[p] - (float)m2 * a2v;

    // Wf row l in fp32: 64 VGPRs. The empty asm with "+v" makes each value
    // asm-defined: the compiler CANNOT sink/rematerialize the loads into the
    // loop (round 9: VGPR_Count=44 proved it reloaded Wf every iteration ->
    // ~512 MB L2 traffic, VALUBusy 8%, 73 us).
    float wfr[64];
#pragma unroll
    for (int j = 0; j < 16; j++) {
        const float4 w4 = reinterpret_cast<const float4*>(Wf)[l * 16 + j];
        wfr[4 * j] = w4.x; wfr[4 * j + 1] = w4.y; wfr[4 * j + 2] = w4.z; wfr[4 * j + 3] = w4.w;
    }
#pragma unroll
    for (int j = 0; j < 64; j++) asm volatile("" : "+v"(wfr[j]));

    __shared__ float red[4][128];

    const int gw = blockIdx.x * 4 + wv;

    // prefetch all iterations' inputs (4 independent loads in flight)
    float xv[KVPW];
    int npv[KVPW];
#pragma unroll
    for (int v = 0; v < KVPW; ++v) {
        const int vx = gw + v * KWAV;
        xv[v] = outp[(vx << 6) + l];
        npv[v] = nump[vx];
    }

    float ts = 0.f, tq = 0.f;
#pragma unroll
    for (int v = 0; v < KVPW; ++v) {
        const int vx = gw + v * KWAV;
        const float h2 = fmaxf(fmaf(a2v, xv[v], c2v), 0.f);
        const float bc = (npv[v] > 0) ? h2 : 0.f;   // lane l holds vf[l]

        float o0 = 0.f, o1 = 0.f, o2 = 0.f, o3 = 0.f;
#pragma unroll
        for (int c = 0; c < 64; c += 4) {
            o0 = fmaf(rdlane(bc, c),     wfr[c],     o0);
            o1 = fmaf(rdlane(bc, c + 1), wfr[c + 1], o1);
            o2 = fmaf(rdlane(bc, c + 2), wfr[c + 2], o2);
            o3 = fmaf(rdlane(bc, c + 3), wfr[c + 3], o3);
        }
        const float out = (o0 + o1) + (o2 + o3);
        outp[(vx << 6) + l] = out;
        ts += out;
        tq = fmaf(out, out, tq);
    }

    red[wv][l] = ts;
    red[wv][64 + l] = tq;
    __syncthreads();
    if (threadIdx.x < 128) {
        const float t = red[0][threadIdx.x] + red[1][threadIdx.x] +
                        red[2][threadIdx.x] + red[3][threadIdx.x];
        atomicAdd(&sfin[threadIdx.x], (double)t);
    }
}

// ---------------- k4: (fused kr3) final BN, in-place, one float4 per thread ----------------
__global__ __launch_bounds__(256) void k4(float* __restrict__ outp,
                                          const double* __restrict__ sfin,
                                          const float* __restrict__ gf,
                                          const float* __restrict__ bfv) {
    __shared__ float af[64], cf[64];
    if (threadIdx.x < 64) {
        const int t = threadIdx.x;
        const double m = sfin[t] * (1.0 / NVOX);
        const double v = sfin[64 + t] * (1.0 / NVOX) - m * m;
        const float aa = gf[t] * rsqrtf((float)v + 1e-5f);
        af[t] = aa;
        cf[t] = bfv[t] - (float)m * aa;
    }
    __syncthreads();
    const int tid = blockIdx.x * blockDim.x + threadIdx.x;   // 512000 threads
    const int o = (tid * 4) & 63;
    float4 v = reinterpret_cast<float4*>(outp)[tid];
    v.x = fmaf(af[o],     v.x, cf[o]);
    v.y = fmaf(af[o + 1], v.y, cf[o + 1]);
    v.z = fmaf(af[o + 2], v.z, cf[o + 2]);
    v.w = fmaf(af[o + 3], v.w, cf[o + 3]);
    reinterpret_cast<float4*>(outp)[tid] = v;
}

extern "C" void kernel_launch(void* const* d_in, const int* in_sizes, int n_in,
                              void* d_out, int out_size, void* d_ws, size_t ws_size,
                              hipStream_t stream) {
    const float* vox    = (const float*)d_in[0];
    const int*   coords = (const int*)d_in[1];
    const int*   nump   = (const int*)d_in[2];
    const float* W1     = (const float*)d_in[3];
    const float* g1     = (const float*)d_in[4];
    const float* b1     = (const float*)d_in[5];
    const float* W2     = (const float*)d_in[6];
    const float* g2     = (const float*)d_in[7];
    const float* b2     = (const float*)d_in[8];
    const float* Wf     = (const float*)d_in[9];
    const float* gf     = (const float*)d_in[10];
    const float* bfv    = (const float*)d_in[11];
    float* out = (float*)d_out;

    double* sF   = (double*)d_ws;        // 44
    double* s2   = sF + 44;              // 64
    double* sfin = sF + 108;             // 128
    float*  wsf  = (float*)d_ws;
    float*  W1S  = wsf + OF_W1S;
    float*  C1S  = wsf + OF_C1S;

    kz<<<1, 256, 0, stream>>>(sF);
    k1<<<2048, 256, 0, stream>>>(vox, coords, sF);
    kr1<<<1, 128, 0, stream>>>(sF, W1, g1, b1, W1S, C1S);
    k2<<<KBLK, 256, 0, stream>>>(vox, coords, nump, W1S, C1S, W2, g2, s2, out);
    k3<<<KBLK, 256, 0, stream>>>(nump, s2, g2, b2, Wf, sfin, out);
    k4<<<2000, 256, 0, stream>>>(out, sfin, gf, bfv);
}

// Round 11
// 229.762 us; speedup vs baseline: 1.2823x; 1.2823x over previous
//
#include <hip/hip_runtime.h>

#define NVOX 32000
#define NPTS 1024000
#define KBLK 2000      // k2 blocks (4 waves each -> 8000 waves)
#define KWAV 8000
#define KVPW 4         // k2 voxels per wave: 8000*4 = 32000
#define BIGF 1e30f

typedef __attribute__((ext_vector_type(8)))  short bf8v;   // 8 bf16 (4 VGPRs)
typedef __attribute__((ext_vector_type(16))) float f16x;   // MFMA 32x32 accum

// split x = hi + lo (both trunc-bf16); residual error ~2^-16 relative
__device__ __forceinline__ void split2(float x, short* hi, short* lo) {
    const unsigned u = __float_as_uint(x);
    *hi = (short)(u >> 16);
    const float r = x - __uint_as_float(u & 0xFFFF0000u);   // exact
    *lo = (short)(__float_as_uint(r) >> 16);
}

// ws layout: doubles first (atomic accumulators), then float params
// doubles: sF[44] | s2[64] | sfin[128] = 236 doubles = 472 floats
#define OF_W1S  480          // 128
#define OF_C1S  (480+128)    // 16

// ---------------- kz: zero the stats accumulators ----------------
__global__ void kz(double* __restrict__ s) {
    if (threadIdx.x < 236) s[threadIdx.x] = 0.0;
}

// ---------------- k1: moment accumulation (Sf[8], Sff upper[36]) ----------------
__global__ __launch_bounds__(256) void k1(const float* __restrict__ vox,
                                          const int* __restrict__ coords,
                                          double* __restrict__ sF) {
    float S[8], U[36];
#pragma unroll
    for (int a = 0; a < 8; a++) S[a] = 0.f;
#pragma unroll
    for (int a = 0; a < 36; a++) U[a] = 0.f;
    const int stride = gridDim.x * blockDim.x;
    for (int i = blockIdx.x * blockDim.x + threadIdx.x; i < NPTS; i += stride) {
        const int vx = i >> 5;
        const float4 q = reinterpret_cast<const float4*>(vox)[i];
        const int4 c4 = reinterpret_cast<const int4*>(coords)[vx];
        const float cx = ((float)c4.w + 0.5f) * 0.16f;
        const float cy = ((float)c4.z + 0.5f) * 0.16f - 39.68f;
        const float cz = ((float)c4.y + 0.5f) * 4.0f  - 3.0f;
        const float f[8] = {q.x, q.y, q.z, q.x - cx, q.y - cy, q.z - cz, q.w, q.z};
        int u = 0;
#pragma unroll
        for (int a = 0; a < 8; a++) {
            S[a] += f[a];
#pragma unroll
            for (int b = a; b < 8; b++) { U[u] = fmaf(f[a], f[b], U[u]); u++; }
        }
    }
    __shared__ float red[4][44];
    const int lane = threadIdx.x & 63, wv = threadIdx.x >> 6;
#pragma unroll
    for (int t = 0; t < 44; t++) {
        float s = (t < 8) ? S[t] : U[t - 8];
#pragma unroll
        for (int m = 1; m < 64; m <<= 1) s += __shfl_xor(s, m);
        if (lane == 0) red[wv][t] = s;
    }
    __syncthreads();
    if (threadIdx.x < 44) {
        const float t = red[0][threadIdx.x] + red[1][threadIdx.x] +
                        red[2][threadIdx.x] + red[3][threadIdx.x];
        atomicAdd(&sF[threadIdx.x], (double)t);
    }
}

// ---------------- kr1: moments -> h1 stats (quadratic form) -> scaled W1 + c1 ----------------
__global__ __launch_bounds__(128) void kr1(const double* __restrict__ sF,
                                           const float* __restrict__ W1,
                                           const float* __restrict__ g1,
                                           const float* __restrict__ b1,
                                           float* __restrict__ w1s,
                                           float* __restrict__ c1s) {
    __shared__ float a1f[16];
    const int t = threadIdx.x;
    if (t < 16) {
        double w[8];
#pragma unroll
        for (int c = 0; c < 8; c++) w[c] = (double)W1[t * 8 + c];
        double mu = 0.0;
#pragma unroll
        for (int c = 0; c < 8; c++) mu += w[c] * sF[c];
        double sq = 0.0;
        int u = 8;
        for (int a = 0; a < 8; a++)
            for (int b = a; b < 8; b++) {
                const double F = sF[u++];
                sq += (a == b ? 1.0 : 2.0) * w[a] * w[b] * F;
            }
        const double m = mu * (1.0 / NPTS);
        const double v = sq * (1.0 / NPTS) - m * m;
        const float inv = rsqrtf((float)v + 1e-3f);
        const float aa = g1[t] * inv;
        a1f[t] = aa;
        c1s[t] = b1[t] - (float)m * aa;
    }
    __syncthreads();
    w1s[t] = a1f[t >> 3] * W1[t];
}

// ---------------- k2: split-bf16 MFMA layer-2, stats of h2pre + fp32 extrema -> d_out ----------------
__global__ __launch_bounds__(256, 4) void k2(const float* __restrict__ vox,
                                             const int* __restrict__ coords,
                                             const int* __restrict__ nump,
                                             const float* __restrict__ w1s,
                                             const float* __restrict__ c1s,
                                             const float* __restrict__ W2,
                                             const float* __restrict__ g2,
                                             double* __restrict__ s2,
                                             float* __restrict__ outp) {
    const int l = threadIdx.x & 63, wv = threadIdx.x >> 6;
    const int p = l & 31, hf = l >> 5;

    bf8v b1h, b1l, b2h, b2l;
#pragma unroll
    for (int i = 0; i < 8; i++) {
        short h_, l_;
        split2(W2[p * 32 + 8 * hf + i], &h_, &l_);       b1h[i] = h_; b1l[i] = l_;
        split2(W2[p * 32 + 16 + 8 * hf + i], &h_, &l_);  b2h[i] = h_; b2l[i] = l_;
    }
    // sign(a2) == sign(g2); work in xs = sign-flipped space so one max covers both.
    const unsigned sbit = (g2[p] >= 0.f) ? 0u : 0x80000000u;

    float tsum = 0.f, tsq = 0.f;
    const int gw = blockIdx.x * 4 + wv;
#pragma unroll 1
    for (int v = 0; v < KVPW; ++v) {
        const int vx = gw + v * KWAV;
        const int4 c4 = reinterpret_cast<const int4*>(coords)[vx];
        const int np = nump[vx];
        const float4 q = reinterpret_cast<const float4*>(vox)[(vx << 5) + p];
        const float cx = ((float)c4.w + 0.5f) * 0.16f;
        const float cy = ((float)c4.z + 0.5f) * 0.16f - 39.68f;
        const float cz = ((float)c4.y + 0.5f) * 4.0f  - 3.0f;
        const float f[8] = {q.x, q.y, q.z, q.x - cx, q.y - cy, q.z - cz, q.w, q.z};
        float mine[8], mx[8];
#pragma unroll
        for (int i = 0; i < 8; i++) {
            float s0 = c1s[i], s1v = c1s[8 + i];
#pragma unroll
            for (int c = 0; c < 8; c++) {
                s0 = fmaf(f[c], w1s[i * 8 + c], s0);
                s1v = fmaf(f[c], w1s[(8 + i) * 8 + c], s1v);
            }
            mine[i] = fmaxf(hf ? s1v : s0, 0.f);
        }
#pragma unroll
        for (int i = 0; i < 8; i++) {
            float m = mine[i];
            m = fmaxf(m, __shfl_xor(m, 1));
            m = fmaxf(m, __shfl_xor(m, 2));
            m = fmaxf(m, __shfl_xor(m, 4));
            m = fmaxf(m, __shfl_xor(m, 8));
            m = fmaxf(m, __shfl_xor(m, 16));
            mx[i] = m;
        }
        const float mk = (p < np) ? 1.f : 0.f;
        bf8v a1h, a1l, a2h, a2l;
#pragma unroll
        for (int i = 0; i < 8; i++) {
            short h_, l_;
            split2(mk * mine[i], &h_, &l_);  a1h[i] = h_; a1l[i] = l_;
            split2(mk * mx[i], &h_, &l_);    a2h[i] = h_; a2l[i] = l_;
        }
        f16x d;
#pragma unroll
        for (int r = 0; r < 16; r++) d[r] = 0.f;
        d = __builtin_amdgcn_mfma_f32_32x32x16_bf16(a1h, b1h, d, 0, 0, 0);
        d = __builtin_amdgcn_mfma_f32_32x32x16_bf16(a1l, b1h, d, 0, 0, 0);
        d = __builtin_amdgcn_mfma_f32_32x32x16_bf16(a1h, b1l, d, 0, 0, 0);
        d = __builtin_amdgcn_mfma_f32_32x32x16_bf16(a2h, b2h, d, 0, 0, 0);
        d = __builtin_amdgcn_mfma_f32_32x32x16_bf16(a2l, b2h, d, 0, 0, 0);
        d = __builtin_amdgcn_mfma_f32_32x32x16_bf16(a2h, b2l, d, 0, 0, 0);

        // stats + extrema in xs-space (lane = channel p, rows (r&3)+8*(r>>2)+4*hf)
        float fx = -BIGF, mxv = -BIGF;
#pragma unroll
        for (int r = 0; r < 16; r++) {
            const int row = (r & 3) + 8 * (r >> 2) + 4 * hf;
            const float x = d[r];
            tsum += x;
            tsq = fmaf(x, x, tsq);
            const float xs = __uint_as_float(__float_as_uint(x) ^ sbit);
            fx = fmaxf(fx, xs);
            mxv = fmaxf(mxv, (row < np) ? xs : -BIGF);
        }
        fx  = fmaxf(fx,  __shfl_xor(fx, 32));
        mxv = fmaxf(mxv, __shfl_xor(mxv, 32));
        // slot l<32: masked extremum of channel l; slot>=32: full extremum of channel l-32
        const float e = __uint_as_float(__float_as_uint(hf ? fx : mxv) ^ sbit);
        outp[(vx << 6) + l] = e;
    }

    tsum += __shfl_xor(tsum, 32);
    tsq  += __shfl_xor(tsq, 32);
    __shared__ float red[4][64];
    if (l < 32) { red[wv][l] = tsum; red[wv][32 + l] = tsq; }
    __syncthreads();
    if (threadIdx.x < 64) {
        const float t = red[0][threadIdx.x] + red[1][threadIdx.x] +
                        red[2][threadIdx.x] + red[3][threadIdx.x];
        atomicAdd(&s2[threadIdx.x], (double)t);
    }
}

// ---------------- k3: MFMA epilogue GEMM: OUT = VF(32000x64) . Wf^T ----------------
// One wave = one 32-voxel x 32-outchannel tile, K=64 in 4 chunks, split-bf16 (12 MFMAs).
// Block = 64 voxels (2 tiles) x 2 halves; in-place safe: all A reads before barrier,
// all stores after. No per-lane weight residency problem: B-frags are straight-line.
__global__ __launch_bounds__(256, 4) void k3(const int* __restrict__ nump,
                                             const double* __restrict__ s2,
                                             const float* __restrict__ g2,
                                             const float* __restrict__ b2,
                                             const float* __restrict__ Wf,
                                             double* __restrict__ sfin,
                                             float* __restrict__ outp) {
    const int l = threadIdx.x & 63, w = threadIdx.x >> 6;
    const int p = l & 31, hf = l >> 5;
    const int half = w & 1;
    const int base = blockIdx.x * 64 + (w >> 1) * 32;   // this wave's 32 voxels
    const int o = half * 32 + p;                        // this lane's out channel

    __shared__ float2 ac[64];        // BN2 (a,c) per vf slot (identical writes from all waves)
    __shared__ float red[4][64];

    {   // fused kr2: BN2 affine for channel l&31
        const int ch = l & 31;
        const double m2 = s2[ch] * (1.0 / NPTS);
        const double v2 = s2[32 + ch] * (1.0 / NPTS) - m2 * m2;
        const float a = g2[ch] * rsqrtf((float)v2 + 1e-3f);
        ac[l] = make_float2(a, b2[ch] - (float)m2 * a);
    }

    // B-frags: B[k][col=p] = Wf[o][k], k-chunks of 16 (8 per hf), split hi/lo
    bf8v bh[4], bl[4];
#pragma unroll
    for (int kc = 0; kc < 4; kc++) {
        const float4 wa = *reinterpret_cast<const float4*>(&Wf[o * 64 + kc * 16 + 8 * hf]);
        const float4 wb = *reinterpret_cast<const float4*>(&Wf[o * 64 + kc * 16 + 8 * hf + 4]);
        const float wv8[8] = {wa.x, wa.y, wa.z, wa.w, wb.x, wb.y, wb.z, wb.w};
#pragma unroll
        for (int i = 0; i < 8; i++) {
            short h_, l_;
            split2(wv8[i], &h_, &l_);
            bh[kc][i] = h_; bl[kc][i] = l_;
        }
    }

    // A raw: lane's voxel row (base+p), vf slots kc*16+8hf+i
    const int np = nump[base + p];
    const float mk = (np > 0) ? 1.f : 0.f;
    float4 qa[4], qb[4];
#pragma unroll
    for (int kc = 0; kc < 4; kc++) {
        qa[kc] = *reinterpret_cast<const float4*>(&outp[(base + p) * 64 + kc * 16 + 8 * hf]);
        qb[kc] = *reinterpret_cast<const float4*>(&outp[(base + p) * 64 + kc * 16 + 8 * hf + 4]);
    }
    __syncthreads();   // every extremum read in the block done before any store below

    f16x d;
#pragma unroll
    for (int r = 0; r < 16; r++) d[r] = 0.f;
#pragma unroll
    for (int kc = 0; kc < 4; kc++) {
        const float xv[8] = {qa[kc].x, qa[kc].y, qa[kc].z, qa[kc].w,
                             qb[kc].x, qb[kc].y, qb[kc].z, qb[kc].w};
        bf8v ah, al;
#pragma unroll
        for (int i = 0; i < 8; i++) {
            const float2 pr = ac[kc * 16 + 8 * hf + i];   // 2 addrs/wave -> broadcast
            const float h = mk * fmaxf(fmaf(pr.x, xv[i], pr.y), 0.f);
            short h_, l_;
            split2(h, &h_, &l_);
            ah[i] = h_; al[i] = l_;
        }
        d = __builtin_amdgcn_mfma_f32_32x32x16_bf16(ah, bh[kc], d, 0, 0, 0);
        d = __builtin_amdgcn_mfma_f32_32x32x16_bf16(al, bh[kc], d, 0, 0, 0);
        d = __builtin_amdgcn_mfma_f32_32x32x16_bf16(ah, bl[kc], d, 0, 0, 0);
    }

    // D: lane holds out[base+row][o], row = (r&3)+8*(r>>2)+4*hf; coalesced stores
    float ts = 0.f, tq = 0.f;
#pragma unroll
    for (int r = 0; r < 16; r++) {
        const int row = (r & 3) + 8 * (r >> 2) + 4 * hf;
        outp[(base + row) * 64 + o] = d[r];
        ts += d[r];
        tq = fmaf(d[r], d[r], tq);
    }
    ts += __shfl_xor(ts, 32);
    tq += __shfl_xor(tq, 32);
    if (l < 32) { red[w][p] = ts; red[w][32 + p] = tq; }
    __syncthreads();
    if (threadIdx.x < 128) {
        const int ch = threadIdx.x & 63;   // out channel
        const int qi = threadIdx.x >> 6;   // 0 = sum, 1 = sqsum
        const int hw = ch >> 5;            // waves hw and hw+2 own this channel half
        const float t = red[hw][qi * 32 + (ch & 31)] + red[hw + 2][qi * 32 + (ch & 31)];
        atomicAdd(&sfin[qi * 64 + ch], (double)t);
    }
}

// ---------------- k4: (fused kr3) final BN, in-place, one float4 per thread ----------------
__global__ __launch_bounds__(256) void k4(float* __restrict__ outp,
                                          const double* __restrict__ sfin,
                                          const float* __restrict__ gf,
                                          const float* __restrict__ bfv) {
    __shared__ float af[64], cf[64];
    if (threadIdx.x < 64) {
        const int t = threadIdx.x;
        const double m = sfin[t] * (1.0 / NVOX);
        const double v = sfin[64 + t] * (1.0 / NVOX) - m * m;
        const float aa = gf[t] * rsqrtf((float)v + 1e-5f);
        af[t] = aa;
        cf[t] = bfv[t] - (float)m * aa;
    }
    __syncthreads();
    const int tid = blockIdx.x * blockDim.x + threadIdx.x;   // 512000 threads
    const int o = (tid * 4) & 63;
    float4 v = reinterpret_cast<float4*>(outp)[tid];
    v.x = fmaf(af[o],     v.x, cf[o]);
    v.y = fmaf(af[o + 1], v.y, cf[o + 1]);
    v.z = fmaf(af[o + 2], v.z, cf[o + 2]);
    v.w = fmaf(af[o + 3], v.w, cf[o + 3]);
    reinterpret_cast<float4*>(outp)[tid] = v;
}

extern "C" void kernel_launch(void* const* d_in, const int* in_sizes, int n_in,
                              void* d_out, int out_size, void* d_ws, size_t ws_size,
                              hipStream_t stream) {
    const float* vox    = (const float*)d_in[0];
    const int*   coords = (const int*)d_in[1];
    const int*   nump   = (const int*)d_in[2];
    const float* W1     = (const float*)d_in[3];
    const float* g1     = (const float*)d_in[4];
    const float* b1     = (const float*)d_in[5];
    const float* W2     = (const float*)d_in[6];
    const float* g2     = (const float*)d_in[7];
    const float* b2     = (const float*)d_in[8];
    const float* Wf     = (const float*)d_in[9];
    const float* gf     = (const float*)d_in[10];
    const float* bfv    = (const float*)d_in[11];
    float* out = (float*)d_out;

    double* sF   = (double*)d_ws;        // 44
    double* s2   = sF + 44;              // 64
    double* sfin = sF + 108;             // 128
    float*  wsf  = (float*)d_ws;
    float*  W1S  = wsf + OF_W1S;
    float*  C1S  = wsf + OF_C1S;

    kz<<<1, 256, 0, stream>>>(sF);
    k1<<<2048, 256, 0, stream>>>(vox, coords, sF);
    kr1<<<1, 128, 0, stream>>>(sF, W1, g1, b1, W1S, C1S);
    k2<<<KBLK, 256, 0, stream>>>(vox, coords, nump, W1S, C1S, W2, g2, s2, out);
    k3<<<500, 256, 0, stream>>>(nump, s2, g2, b2, Wf, sfin, out);
    k4<<<2000, 256, 0, stream>>>(out, sfin, gf, bfv);
}

// Round 13
// 179.594 us; speedup vs baseline: 1.6405x; 1.2793x over previous
//
#include <hip/hip_runtime.h>

#define NVOX 32000
#define NPTS 1024000
#define KBLK 1000      // k2 blocks (4 waves each -> 4000 waves)
#define KWAV 4000
#define KVPW 8         // k2 voxels per wave: 4000*8 = 32000
#define BIGF 1e30f

typedef __attribute__((ext_vector_type(8)))  short bf8v;   // 8 bf16 (4 VGPRs)
typedef __attribute__((ext_vector_type(16))) float f16x;   // MFMA 32x32 accum

// split x = hi + lo (both trunc-bf16); residual error ~2^-16 relative
__device__ __forceinline__ void split2(float x, short* hi, short* lo) {
    const unsigned u = __float_as_uint(x);
    *hi = (short)(u >> 16);
    const float r = x - __uint_as_float(u & 0xFFFF0000u);   // exact
    *lo = (short)(__float_as_uint(r) >> 16);
}

// ws layout: doubles first (atomic accumulators), then float params
// doubles: sF[44] | s2[64] | sfin[128] = 236 doubles = 472 floats
#define OF_W1S  480          // 128
#define OF_C1S  (480+128)    // 16

// ---------------- kz: zero the stats accumulators ----------------
__global__ void kz(double* __restrict__ s) {
    if (threadIdx.x < 236) s[threadIdx.x] = 0.0;
}

// ---------------- k1: moment accumulation (Sf[8], Sff upper[36]) ----------------
// 384 blocks: same-address fp64 atomic chain = 384 deep (2048 was suspect ~50us drain).
__global__ __launch_bounds__(256) void k1(const float* __restrict__ vox,
                                          const int* __restrict__ coords,
                                          double* __restrict__ sF) {
    float S[8], U[36];
#pragma unroll
    for (int a = 0; a < 8; a++) S[a] = 0.f;
#pragma unroll
    for (int a = 0; a < 36; a++) U[a] = 0.f;
    const int stride = gridDim.x * blockDim.x;
    for (int i = blockIdx.x * blockDim.x + threadIdx.x; i < NPTS; i += stride) {
        const int vx = i >> 5;
        const float4 q = reinterpret_cast<const float4*>(vox)[i];
        const int4 c4 = reinterpret_cast<const int4*>(coords)[vx];
        const float cx = ((float)c4.w + 0.5f) * 0.16f;
        const float cy = ((float)c4.z + 0.5f) * 0.16f - 39.68f;
        const float cz = ((float)c4.y + 0.5f) * 4.0f  - 3.0f;
        const float f[8] = {q.x, q.y, q.z, q.x - cx, q.y - cy, q.z - cz, q.w, q.z};
        int u = 0;
#pragma unroll
        for (int a = 0; a < 8; a++) {
            S[a] += f[a];
#pragma unroll
            for (int b = a; b < 8; b++) { U[u] = fmaf(f[a], f[b], U[u]); u++; }
        }
    }
    __shared__ float red[4][44];
    const int lane = threadIdx.x & 63, wv = threadIdx.x >> 6;
#pragma unroll
    for (int t = 0; t < 44; t++) {
        float s = (t < 8) ? S[t] : U[t - 8];
#pragma unroll
        for (int m = 1; m < 64; m <<= 1) s += __shfl_xor(s, m);
        if (lane == 0) red[wv][t] = s;
    }
    __syncthreads();
    if (threadIdx.x < 44) {
        const float t = red[0][threadIdx.x] + red[1][threadIdx.x] +
                        red[2][threadIdx.x] + red[3][threadIdx.x];
        atomicAdd(&sF[threadIdx.x], (double)t);
    }
}

// ---------------- kr1: moments -> h1 stats (quadratic form) -> scaled W1 + c1 ----------------
__global__ __launch_bounds__(128) void kr1(const double* __restrict__ sF,
                                           const float* __restrict__ W1,
                                           const float* __restrict__ g1,
                                           const float* __restrict__ b1,
                                           float* __restrict__ w1s,
                                           float* __restrict__ c1s) {
    __shared__ float a1f[16];
    const int t = threadIdx.x;
    if (t < 16) {
        double w[8];
#pragma unroll
        for (int c = 0; c < 8; c++) w[c] = (double)W1[t * 8 + c];
        double mu = 0.0;
#pragma unroll
        for (int c = 0; c < 8; c++) mu += w[c] * sF[c];
        double sq = 0.0;
        int u = 8;
        for (int a = 0; a < 8; a++)
            for (int b = a; b < 8; b++) {
                const double F = sF[u++];
                sq += (a == b ? 1.0 : 2.0) * w[a] * w[b] * F;
            }
        const double m = mu * (1.0 / NPTS);
        const double v = sq * (1.0 / NPTS) - m * m;
        const float inv = rsqrtf((float)v + 1e-3f);
        const float aa = g1[t] * inv;
        a1f[t] = aa;
        c1s[t] = b1[t] - (float)m * aa;
    }
    __syncthreads();
    w1s[t] = a1f[t >> 3] * W1[t];
}

// ---------------- k2: MFMA layer-2 (h1-half) + rank-1 max-half, stats + extrema ----------------
// Max-half of cb is wave-uniform per channel: h2pre[pt][o] = MFMA(mk*h1) + mk[pt]*dvox[o],
// dvox[o] = sum_c W2[o][16+c]*mx[c] -- 8 reg-FMAs + 1 shfl, exact fp32 (no bf16 there).
__global__ __launch_bounds__(256, 4) void k2(const float* __restrict__ vox,
                                             const int* __restrict__ coords,
                                             const int* __restrict__ nump,
                                             const float* __restrict__ w1s,
                                             const float* __restrict__ c1s,
                                             const float* __restrict__ W2,
                                             const float* __restrict__ g2,
                                             double* __restrict__ s2,
                                             float* __restrict__ outp) {
    const int l = threadIdx.x & 63, wv = threadIdx.x >> 6;
    const int p = l & 31, hf = l >> 5;

    bf8v b1h, b1l;
    float w2f[8];
#pragma unroll
    for (int i = 0; i < 8; i++) {
        short h_, l_;
        split2(W2[p * 32 + 8 * hf + i], &h_, &l_);
        b1h[i] = h_; b1l[i] = l_;
        w2f[i] = W2[p * 32 + 16 + 8 * hf + i];
    }
    // sign(a2) == sign(g2); work in xs = sign-flipped space so one max covers both.
    const unsigned sbit = (g2[p] >= 0.f) ? 0u : 0x80000000u;

    float tsum = 0.f, tsq = 0.f;
    const int gw = blockIdx.x * 4 + wv;
#pragma unroll 1
    for (int v = 0; v < KVPW; ++v) {
        const int vx = gw + v * KWAV;
        const int4 c4 = reinterpret_cast<const int4*>(coords)[vx];
        const int np = nump[vx];
        const float4 q = reinterpret_cast<const float4*>(vox)[(vx << 5) + p];
        const float cx = ((float)c4.w + 0.5f) * 0.16f;
        const float cy = ((float)c4.z + 0.5f) * 0.16f - 39.68f;
        const float cz = ((float)c4.y + 0.5f) * 4.0f  - 3.0f;
        const float f[8] = {q.x, q.y, q.z, q.x - cx, q.y - cy, q.z - cz, q.w, q.z};
        float mine[8], mx[8];
#pragma unroll
        for (int i = 0; i < 8; i++) {
            float s0 = c1s[i], s1v = c1s[8 + i];
#pragma unroll
            for (int c = 0; c < 8; c++) {
                s0 = fmaf(f[c], w1s[i * 8 + c], s0);
                s1v = fmaf(f[c], w1s[(8 + i) * 8 + c], s1v);
            }
            mine[i] = fmaxf(hf ? s1v : s0, 0.f);
        }
#pragma unroll
        for (int i = 0; i < 8; i++) {
            float m = mine[i];
            m = fmaxf(m, __shfl_xor(m, 1));
            m = fmaxf(m, __shfl_xor(m, 2));
            m = fmaxf(m, __shfl_xor(m, 4));
            m = fmaxf(m, __shfl_xor(m, 8));
            m = fmaxf(m, __shfl_xor(m, 16));
            mx[i] = m;
        }
        // dvox: per-lane partial over its 8 k-slots, fold across hf halves
        float dv = 0.f;
#pragma unroll
        for (int i = 0; i < 8; i++) dv = fmaf(w2f[i], mx[i], dv);
        const float dvox = dv + __shfl_xor(dv, 32);   // uniform per (voxel, channel p)

        const float mk = (p < np) ? 1.f : 0.f;
        bf8v a1h, a1l;
#pragma unroll
        for (int i = 0; i < 8; i++) {
            short h_, l_;
            split2(mk * mine[i], &h_, &l_);
            a1h[i] = h_; a1l[i] = l_;
        }
        f16x d;
#pragma unroll
        for (int r = 0; r < 16; r++) d[r] = 0.f;
        d = __builtin_amdgcn_mfma_f32_32x32x16_bf16(a1h, b1h, d, 0, 0, 0);
        d = __builtin_amdgcn_mfma_f32_32x32x16_bf16(a1l, b1h, d, 0, 0, 0);
        d = __builtin_amdgcn_mfma_f32_32x32x16_bf16(a1h, b1l, d, 0, 0, 0);

        // stats + extrema in xs-space (lane = channel p, rows (r&3)+8*(r>>2)+4*hf)
        float fx = -BIGF, mxv = -BIGF;
#pragma unroll
        for (int r = 0; r < 16; r++) {
            const int row = (r & 3) + 8 * (r >> 2) + 4 * hf;
            const float x = d[r] + ((row < np) ? dvox : 0.f);
            tsum += x;
            tsq = fmaf(x, x, tsq);
            const float xs = __uint_as_float(__float_as_uint(x) ^ sbit);
            fx = fmaxf(fx, xs);
            mxv = fmaxf(mxv, (row < np) ? xs : -BIGF);
        }
        fx  = fmaxf(fx,  __shfl_xor(fx, 32));
        mxv = fmaxf(mxv, __shfl_xor(mxv, 32));
        // slot l<32: masked extremum of channel l; slot>=32: full extremum of channel l-32
        const float e = __uint_as_float(__float_as_uint(hf ? fx : mxv) ^ sbit);
        outp[(vx << 6) + l] = e;
    }

    tsum += __shfl_xor(tsum, 32);
    tsq  += __shfl_xor(tsq, 32);
    __shared__ float red[4][64];
    if (l < 32) { red[wv][l] = tsum; red[wv][32 + l] = tsq; }
    __syncthreads();
    if (threadIdx.x < 64) {
        const float t = red[0][threadIdx.x] + red[1][threadIdx.x] +
                        red[2][threadIdx.x] + red[3][threadIdx.x];
        atomicAdd(&s2[threadIdx.x], (double)t);
    }
}

// ---------------- k3: MFMA epilogue GEMM: OUT = VF(32000x64) . Wf^T ----------------
__global__ __launch_bounds__(256, 4) void k3(const int* __restrict__ nump,
                                             const double* __restrict__ s2,
                                             const float* __restrict__ g2,
                                             const float* __restrict__ b2,
                                             const float* __restrict__ Wf,
                                             double* __restrict__ sfin,
                                             float* __restrict__ outp) {
    const int l = threadIdx.x & 63, w = threadIdx.x >> 6;
    const int p = l & 31, hf = l >> 5;
    const int half = w & 1;
    const int base = blockIdx.x * 64 + (w >> 1) * 32;   // this wave's 32 voxels
    const int o = half * 32 + p;                        // this lane's out channel

    __shared__ float2 ac[64];        // BN2 (a,c) per vf slot
    __shared__ float red[4][64];

    {   // fused kr2: BN2 affine for channel l&31
        const int ch = l & 31;
        const double m2 = s2[ch] * (1.0 / NPTS);
        const double v2 = s2[32 + ch] * (1.0 / NPTS) - m2 * m2;
        const float a = g2[ch] * rsqrtf((float)v2 + 1e-3f);
        ac[l] = make_float2(a, b2[ch] - (float)m2 * a);
    }

    // B-frags: B[k][col=p] = Wf[o][k], k-chunks of 16 (8 per hf), split hi/lo
    bf8v bh[4], bl[4];
#pragma unroll
    for (int kc = 0; kc < 4; kc++) {
        const float4 wa = *reinterpret_cast<const float4*>(&Wf[o * 64 + kc * 16 + 8 * hf]);
        const float4 wb = *reinterpret_cast<const float4*>(&Wf[o * 64 + kc * 16 + 8 * hf + 4]);
        const float wv8[8] = {wa.x, wa.y, wa.z, wa.w, wb.x, wb.y, wb.z, wb.w};
#pragma unroll
        for (int i = 0; i < 8; i++) {
            short h_, l_;
            split2(wv8[i], &h_, &l_);
            bh[kc][i] = h_; bl[kc][i] = l_;
        }
    }

    // A raw: lane's voxel row (base+p), vf slots kc*16+8hf+i
    const int np = nump[base + p];
    const float mk = (np > 0) ? 1.f : 0.f;
    float4 qa[4], qb[4];
#pragma unroll
    for (int kc = 0; kc < 4; kc++) {
        qa[kc] = *reinterpret_cast<const float4*>(&outp[(base + p) * 64 + kc * 16 + 8 * hf]);
        qb[kc] = *reinterpret_cast<const float4*>(&outp[(base + p) * 64 + kc * 16 + 8 * hf + 4]);
    }
    __syncthreads();   // every extremum read in the block done before any store below

    f16x d;
#pragma unroll
    for (int r = 0; r < 16; r++) d[r] = 0.f;
#pragma unroll
    for (int kc = 0; kc < 4; kc++) {
        const float xv[8] = {qa[kc].x, qa[kc].y, qa[kc].z, qa[kc].w,
                             qb[kc].x, qb[kc].y, qb[kc].z, qb[kc].w};
        bf8v ah, al;
#pragma unroll
        for (int i = 0; i < 8; i++) {
            const float2 pr = ac[kc * 16 + 8 * hf + i];   // 2 addrs/wave -> broadcast
            const float h = mk * fmaxf(fmaf(pr.x, xv[i], pr.y), 0.f);
            short h_, l_;
            split2(h, &h_, &l_);
            ah[i] = h_; al[i] = l_;
        }
        d = __builtin_amdgcn_mfma_f32_32x32x16_bf16(ah, bh[kc], d, 0, 0, 0);
        d = __builtin_amdgcn_mfma_f32_32x32x16_bf16(al, bh[kc], d, 0, 0, 0);
        d = __builtin_amdgcn_mfma_f32_32x32x16_bf16(ah, bl[kc], d, 0, 0, 0);
    }

    // D: lane holds out[base+row][o], row = (r&3)+8*(r>>2)+4*hf; coalesced stores
    float ts = 0.f, tq = 0.f;
#pragma unroll
    for (int r = 0; r < 16; r++) {
        const int row = (r & 3) + 8 * (r >> 2) + 4 * hf;
        outp[(base + row) * 64 + o] = d[r];
        ts += d[r];
        tq = fmaf(d[r], d[r], tq);
    }
    ts += __shfl_xor(ts, 32);
    tq += __shfl_xor(tq, 32);
    if (l < 32) { red[w][p] = ts; red[w][32 + p] = tq; }
    __syncthreads();
    if (threadIdx.x < 128) {
        const int ch = threadIdx.x & 63;   // out channel
        const int qi = threadIdx.x >> 6;   // 0 = sum, 1 = sqsum
        const int hw = ch >> 5;            // waves hw and hw+2 own this channel half
        const float t = red[hw][qi * 32 + (ch & 31)] + red[hw + 2][qi * 32 + (ch & 31)];
        atomicAdd(&sfin[qi * 64 + ch], (double)t);
    }
}

// ---------------- k4: (fused kr3) final BN, in-place, one float4 per thread ----------------
__global__ __launch_bounds__(256) void k4(float* __restrict__ outp,
                                          const double* __restrict__ sfin,
                                          const float* __restrict__ gf,
                                          const float* __restrict__ bfv) {
    __shared__ float af[64], cf[64];
    if (threadIdx.x < 64) {
        const int t = threadIdx.x;
        const double m = sfin[t] * (1.0 / NVOX);
        const double v = sfin[64 + t] * (1.0 / NVOX) - m * m;
        const float aa = gf[t] * rsqrtf((float)v + 1e-5f);
        af[t] = aa;
        cf[t] = bfv[t] - (float)m * aa;
    }
    __syncthreads();
    const int tid = blockIdx.x * blockDim.x + threadIdx.x;   // 512000 threads
    const int o = (tid * 4) & 63;
    float4 v = reinterpret_cast<float4*>(outp)[tid];
    v.x = fmaf(af[o],     v.x, cf[o]);
    v.y = fmaf(af[o + 1], v.y, cf[o + 1]);
    v.z = fmaf(af[o + 2], v.z, cf[o + 2]);
    v.w = fmaf(af[o + 3], v.w, cf[o + 3]);
    reinterpret_cast<float4*>(outp)[tid] = v;
}

extern "C" void kernel_launch(void* const* d_in, const int* in_sizes, int n_in,
                              void* d_out, int out_size, void* d_ws, size_t ws_size,
                              hipStream_t stream) {
    const float* vox    = (const float*)d_in[0];
    const int*   coords = (const int*)d_in[1];
    const int*   nump   = (const int*)d_in[2];
    const float* W1     = (const float*)d_in[3];
    const float* g1     = (const float*)d_in[4];
    const float* b1     = (const float*)d_in[5];
    const float* W2     = (const float*)d_in[6];
    const float* g2     = (const float*)d_in[7];
    const float* b2     = (const float*)d_in[8];
    const float* Wf     = (const float*)d_in[9];
    const float* gf     = (const float*)d_in[10];
    const float* bfv    = (const float*)d_in[11];
    float* out = (float*)d_out;

    double* sF   = (double*)d_ws;        // 44
    double* s2   = sF + 44;              // 64
    double* sfin = sF + 108;             // 128
    float*  wsf  = (float*)d_ws;
    float*  W1S  = wsf + OF_W1S;
    float*  C1S  = wsf + OF_C1S;

    kz<<<1, 256, 0, stream>>>(sF);
    k1<<<384, 256, 0, stream>>>(vox, coords, sF);
    kr1<<<1, 128, 0, stream>>>(sF, W1, g1, b1, W1S, C1S);
    k2<<<KBLK, 256, 0, stream>>>(vox, coords, nump, W1S, C1S, W2, g2, s2, out);
    k3<<<500, 256, 0, stream>>>(nump, s2, g2, b2, Wf, sfin, out);
    k4<<<2000, 256, 0, stream>>>(out, sfin, gf, bfv);
}